// Round 13
// baseline (124.140 us; speedup 1.0000x reference)
//
#include <hip/hip_runtime.h>
#include <hip/hip_bf16.h>

typedef _Float16 f16;
typedef _Float16 f16x8 __attribute__((ext_vector_type(8)));
typedef _Float16 f16x4 __attribute__((ext_vector_type(4)));
typedef float f32x4 __attribute__((ext_vector_type(4)));
typedef int i32x4 __attribute__((ext_vector_type(4)));

#define LDS_LOAD16(gptr, lptr)                                                             \
  __builtin_amdgcn_global_load_lds(                                                        \
      (const __attribute__((address_space(1))) unsigned int*)(gptr),                       \
      (__attribute__((address_space(3))) unsigned int*)(lptr), 16, 0, 0)

// 0.125 (1/sqrt(HD)) * log2(e): folded into Q so QK^T yields log2e-scaled scores
#define ALPHA 0.18033688f
// masked score: reference sets score=1e-9 (log2e domain)
#define MASKVAL 1.44269504e-9f

// ---------------------------------------------------------------------------
// fused fp32 -> fp16 conversion for x + 4 weight matrices
// ---------------------------------------------------------------------------
__global__ __launch_bounds__(256) void conv_all(const float* __restrict__ x,
                                                const float* __restrict__ Wq,
                                                const float* __restrict__ Wk,
                                                const float* __restrict__ Wv,
                                                const float* __restrict__ Wo,
                                                f16* __restrict__ xh, f16* __restrict__ wqh,
                                                f16* __restrict__ wkh, f16* __restrict__ wvh,
                                                f16* __restrict__ woh) {
  int i = blockIdx.x * 256 + threadIdx.x;
  const float* src;
  f16* dst;
  int off;
  if (i < 524288) {
    src = x; dst = xh; off = i;
  } else {
    int j = i - 524288;
    int w = j >> 17;
    off = j & 131071;
    src = (w == 0) ? Wq : (w == 1) ? Wk : (w == 2) ? Wv : Wo;
    dst = (w == 0) ? wqh : (w == 1) ? wkh : (w == 2) ? wvh : woh;
  }
  const float4* s4 = (const float4*)src;
  float4 a = s4[2 * off];
  float4 b = s4[2 * off + 1];
  f16x8 o = {(f16)a.x, (f16)a.y, (f16)a.z, (f16)a.w,
             (f16)b.x, (f16)b.y, (f16)b.z, (f16)b.w};
  *(f16x8*)(dst + (size_t)off * 8) = o;
}

// ---------------------------------------------------------------------------
// Fused QKV projection: z=0 -> Q (scaled by ALPHA), z=1 -> K,
// z=2 -> V in MFMA-fragment-tiled layout:
//   Vf[head][kvtile(32)][frag(k2*4+df)][lane(64)][e(8)]  (f16)
// so attention can load V B-fragments as lane-contiguous b128 (L1-broadcast
// across the 4 waves of a block).  2-phase pipeline, vmcnt(4), dbuf LDS,
// XCD-chunked swizzle.
// ---------------------------------------------------------------------------
__global__ __launch_bounds__(256) void gemm_qkv(const f16* __restrict__ A,
                                                const f16* __restrict__ W0,
                                                const f16* __restrict__ W1,
                                                const f16* __restrict__ W2,
                                                const float* __restrict__ b0,
                                                const float* __restrict__ b1,
                                                const float* __restrict__ b2,
                                                f16* __restrict__ qo, f16* __restrict__ ko,
                                                f16* __restrict__ vo) {
  constexpr int K = 1024, BM = 128, BK = 32, NKT = K / BK;
  __shared__ f16 aT[2][BM * BK];
  __shared__ f16 bT[2][BM * BK];
  const int rid = (blockIdx.x & 7) * 96 + (blockIdx.x >> 3);
  const int z = rid >> 8;
  const f16* Bw = (z == 0) ? W0 : (z == 1) ? W1 : W2;
  const float* bias = (z == 0) ? b0 : (z == 1) ? b1 : b2;
  const int tid = threadIdx.x, wid = tid >> 6, lane = tid & 63;
  const int mb = ((rid >> 3) & 31) * BM, nb = (rid & 7) * BM;
  const int wr = wid >> 1, wc = wid & 1;
  const int lr = lane & 15, hi = lane >> 4;

  f32x4 acc[4][4] = {};

  const int r0 = tid >> 2, s0 = tid & 3;
  const int ci1 = 256 + tid, r1 = ci1 >> 2, s1 = ci1 & 3;

#define STAGE_QKV(bb, kt)                                                                   \
  do {                                                                                      \
    const int kb_ = (kt) * BK;                                                              \
    LDS_LOAD16(A + (size_t)(mb + r0) * K + kb_ + s0 * 8, (char*)aT[bb] + wid * 1024);       \
    LDS_LOAD16(Bw + (size_t)(nb + r0) * K + kb_ + s0 * 8, (char*)bT[bb] + wid * 1024);      \
    LDS_LOAD16(A + (size_t)(mb + r1) * K + kb_ + s1 * 8, (char*)aT[bb] + 4096 + wid * 1024);\
    LDS_LOAD16(Bw + (size_t)(nb + r1) * K + kb_ + s1 * 8, (char*)bT[bb] + 4096 + wid * 1024);\
  } while (0)

  STAGE_QKV(0, 0);
  for (int kt = 0; kt < NKT; ++kt) {
    const int p = kt & 1;
    if (kt + 1 < NKT) {
      STAGE_QKV(p ^ 1, kt + 1);
      asm volatile("s_waitcnt vmcnt(4)" ::: "memory");
    } else {
      asm volatile("s_waitcnt vmcnt(0)" ::: "memory");
    }
    __builtin_amdgcn_s_barrier();

    f16x8 af[4], bf[4];
#pragma unroll
    for (int i = 0; i < 4; ++i) af[i] = *(const f16x8*)&aT[p][(wr * 64 + i * 16 + lr) * BK + hi * 8];
#pragma unroll
    for (int j = 0; j < 4; ++j) bf[j] = *(const f16x8*)&bT[p][(wc * 64 + j * 16 + lr) * BK + hi * 8];
    __builtin_amdgcn_s_setprio(1);
#pragma unroll
    for (int i = 0; i < 4; ++i)
#pragma unroll
      for (int j = 0; j < 4; ++j)
        acc[i][j] = __builtin_amdgcn_mfma_f32_16x16x32_f16(af[i], bf[j], acc[i][j], 0, 0, 0);
    __builtin_amdgcn_s_setprio(0);
    __builtin_amdgcn_s_barrier();
  }

  const float scale = (z == 0) ? ALPHA : 1.0f;
#pragma unroll
  for (int i = 0; i < 4; ++i) {
#pragma unroll
    for (int j = 0; j < 4; ++j) {
      const int row = mb + wr * 64 + i * 16 + hi * 4;
      const int col = nb + wc * 64 + j * 16 + lr;
      const float bv = bias[col];
      const int hh = col >> 6, dd = col & 63;
      if (z == 2) {
        // V fragment-tiled write (derivation: kvt=i*16+hi*4+r, d=j*16+lr ->
        // frag=(i>>1)*4+j, lane'=((kvt>>3)&3)*16+lr, e=kvt&7; r spans e
        // contiguously since hi*4 & 7 is 0 or 4).
        const int bb = row >> 11, l = row & 2047;
        const int head2 = bb * 16 + hh;
        const int kvt = l & 63;
        const int frag = (kvt >> 5) * 4 + j;
        const int lane2 = ((kvt >> 3) & 3) * 16 + lr;
        const int e0 = kvt & 7;
        f16x4 v4;
#pragma unroll
        for (int r = 0; r < 4; ++r) v4[r] = (f16)(acc[i][j][r] + bv);
        *(f16x4*)&vo[(size_t)(head2 * 32 + (l >> 6)) * 4096 + frag * 512 + lane2 * 8 + e0] = v4;
      } else {
        f16* o = z ? ko : qo;
#pragma unroll
        for (int r = 0; r < 4; ++r) {
          const int m2 = row + r;
          const int bb = m2 >> 11, l = m2 & 2047;
          o[((((size_t)bb * 16 + hh) * 2048 + l) * 64) + dd] = (f16)((acc[i][j][r] + bv) * scale);
        }
      }
    }
  }
}

// ---------------------------------------------------------------------------
// Output projection: 64(M)x128(N) tile, 2-phase pipeline, XCD-chunked swizzle.
// ---------------------------------------------------------------------------
__global__ __launch_bounds__(256) void gemm_o(const f16* __restrict__ A,
                                              const f16* __restrict__ W,
                                              const float* __restrict__ bias,
                                              float* __restrict__ out) {
  constexpr int K = 1024, N = 1024, BK = 32, NKT = K / BK;
  __shared__ f16 aT[2][64 * BK];
  __shared__ f16 bT[2][128 * BK];
  const int rid = (blockIdx.x & 7) * 64 + (blockIdx.x >> 3);
  const int tid = threadIdx.x, wid = tid >> 6, lane = tid & 63;
  const int lr = lane & 15, hi = lane >> 4;
  const int mb = (rid >> 3) * 64, nb = (rid & 7) * 128;
  const int wr = wid >> 1, wc = wid & 1;
  f32x4 acc[2][4] = {};
  const int ra = tid >> 2, sa = tid & 3;
  const int rb1 = (256 + tid) >> 2, sb1 = (256 + tid) & 3;

#define STAGE_O(bb, kt)                                                                     \
  do {                                                                                      \
    const int kb_ = (kt) * BK;                                                              \
    LDS_LOAD16(A + (size_t)(mb + ra) * K + kb_ + sa * 8, (char*)aT[bb] + wid * 1024);       \
    LDS_LOAD16(W + (size_t)(nb + ra) * K + kb_ + sa * 8, (char*)bT[bb] + wid * 1024);       \
    LDS_LOAD16(W + (size_t)(nb + rb1) * K + kb_ + sb1 * 8, (char*)bT[bb] + 4096 + wid * 1024);\
  } while (0)

  STAGE_O(0, 0);
  for (int kt = 0; kt < NKT; ++kt) {
    const int p = kt & 1;
    if (kt + 1 < NKT) {
      STAGE_O(p ^ 1, kt + 1);
      asm volatile("s_waitcnt vmcnt(3)" ::: "memory");
    } else {
      asm volatile("s_waitcnt vmcnt(0)" ::: "memory");
    }
    __builtin_amdgcn_s_barrier();
    f16x8 af[2], bf[4];
#pragma unroll
    for (int i = 0; i < 2; ++i) af[i] = *(const f16x8*)&aT[p][(wr * 32 + i * 16 + lr) * BK + hi * 8];
#pragma unroll
    for (int j = 0; j < 4; ++j) bf[j] = *(const f16x8*)&bT[p][(wc * 64 + j * 16 + lr) * BK + hi * 8];
    __builtin_amdgcn_s_setprio(1);
#pragma unroll
    for (int i = 0; i < 2; ++i)
#pragma unroll
      for (int j = 0; j < 4; ++j)
        acc[i][j] = __builtin_amdgcn_mfma_f32_16x16x32_f16(af[i], bf[j], acc[i][j], 0, 0, 0);
    __builtin_amdgcn_s_setprio(0);
    __builtin_amdgcn_s_barrier();
  }
#pragma unroll
  for (int i = 0; i < 2; ++i)
#pragma unroll
    for (int j = 0; j < 4; ++j) {
      const int col = nb + wc * 64 + j * 16 + lr;
      const float bv = bias[col];
#pragma unroll
      for (int r = 0; r < 4; ++r)
        out[(size_t)(mb + wr * 32 + i * 16 + hi * 4 + r) * N + col] = acc[i][j][r] + bv;
    }
}

// ---------------------------------------------------------------------------
// Flash attention v7: v5 structure (4 waves x 16 q, 16x16x32 MFMA) with V
// moved OUT of LDS: V B-fragments loaded from the fragment-tiled Vf buffer
// straight into registers (coalesced b128; L1 broadcasts across the block's
// 4 waves).  LDS holds only K (2 x 8 KB dbuf).  DS traffic per wave-tile
// halves (8 reads + 2 stage-writes).  P transpose in VALU (permlane32+16),
// row-sums via ones-MFMA, mask all-ones fast path, p = exp2(score*log2e).
// ---------------------------------------------------------------------------
__global__ __launch_bounds__(256, 4) void attn4w(const f16* __restrict__ Qh,
                                                 const f16* __restrict__ Kh,
                                                 const f16* __restrict__ Vf,
                                                 const int* __restrict__ mask,
                                                 f16* __restrict__ Oa) {
  constexpr int L = 2048, HD = 64, H = 16, NT = L / 64;
  // [parity][ K 8KB ] = 16 KB
  __shared__ __align__(16) char ldsb[16384];

  const int tid = threadIdx.x, w = tid >> 6, lane = tid & 63;
  const int lr = lane & 15, hi = lane >> 4;
  const int sw = lr & 7;

  // XCD-bijective remap: bid bits [2:0]=xcd, [7:3]=qb, [9:8]=head-in-xcd
  const int bid = blockIdx.x;  // 1024 blocks
  const int head = (bid & 7) * 4 + (bid >> 8);
  const int qb = (bid >> 3) & 31;
  const int b = head >> 4, h = head & 15;
  const int qr0 = qb * 64 + w * 16;

  const f16* Qb = Qh + (size_t)head * L * HD;
  const f16* Kb = Kh + (size_t)head * L * HD;
  const f16* Vb = Vf + (size_t)head * 32 * 4096;  // fragment-tiled
  const int* mrow = mask + b * L;

  // whole-row mask scan (wave-uniform fast path; mask is 0/1 ints)
  int mred = 1;
  {
    const int4* m4 = (const int4*)mrow;
#pragma unroll
    for (int j = 0; j < 8; ++j) {
      int4 v = m4[lane + j * 64];
      mred &= v.x & v.y & v.z & v.w;
    }
  }
  const bool allm = __all(mred == 1);

  // K staging: wave w stages rows [w*16, w*16+16) (2 chunks of 8 rows);
  // source chunk pre-swizzled by row&7, LDS dest linear.
  const int srow = lane >> 3;
  const int schk = (lane & 7) ^ srow;

#define STAGE_K(bb, kt)                                                                     \
  _Pragma("unroll") for (int c = 0; c < 2; ++c) {                                           \
    LDS_LOAD16(Kb + (size_t)((kt) * 64 + w * 16 + c * 8 + srow) * HD + schk * 8,            \
               ldsb + (bb) * 8192 + w * 2048 + c * 1024);                                   \
  }

  // per-lane LDS read bases (k2=0 / k2=1 chunk swizzle), all else via imms
  const char* kbase0 = ldsb + lr * 128 + ((hi ^ sw) * 16);
  const char* kbase1 = ldsb + lr * 128 + (((4 + hi) ^ sw) * 16);

  // Q fragments (B-operand), resident for the whole kernel
  f16x8 qf[2];
#pragma unroll
  for (int k2 = 0; k2 < 2; ++k2)
    qf[k2] = *(const f16x8*)&Qb[(size_t)(qr0 + lr) * HD + k2 * 32 + hi * 8];

  f32x4 oacc[4] = {};
  f32x4 lacc = {};
  const f32x4 zacc = {0.f, 0.f, 0.f, 0.f};
  const f16x8 ones = {1, 1, 1, 1, 1, 1, 1, 1};

  int4 mvA[4], mvB[4];
  if (!allm) {
#pragma unroll
    for (int nf = 0; nf < 4; ++nf) mvA[nf] = *(const int4*)&mrow[nf * 16 + hi * 4];
  }
  STAGE_K(0, 0);

#define ATTN_ITER(kt, P, MVR, MVL)                                                          \
  do {                                                                                      \
    asm volatile("s_waitcnt vmcnt(0)" ::: "memory");                                        \
    __builtin_amdgcn_s_barrier();                                                           \
    /* V(t) fragment loads -> registers (compiler inserts the data-dep wait) */             \
    f16x8 vreg[2][4];                                                                       \
    _Pragma("unroll") for (int k2 = 0; k2 < 2; ++k2)                                        \
        _Pragma("unroll") for (int df = 0; df < 4; ++df)                                    \
            vreg[k2][df] = *(const f16x8*)&Vb[(size_t)(kt) * 4096 + (k2 * 4 + df) * 512 +   \
                                              lane * 8];                                    \
    if ((kt) + 1 < NT) {                                                                    \
      if (!allm) {                                                                          \
        _Pragma("unroll") for (int nf = 0; nf < 4; ++nf)                                    \
            MVL[nf] = *(const int4*)&mrow[((kt) + 1) * 64 + nf * 16 + hi * 4];              \
      }                                                                                     \
      STAGE_K((P) ^ 1, (kt) + 1);                                                           \
    }                                                                                       \
    f16x8 kf[4][2];                                                                         \
    _Pragma("unroll") for (int nf = 0; nf < 4; ++nf) {                                      \
      kf[nf][0] = *(const f16x8*)(kbase0 + (P) * 8192 + nf * 2048);                         \
      kf[nf][1] = *(const f16x8*)(kbase1 + (P) * 8192 + nf * 2048);                         \
    }                                                                                       \
    f32x4 s[4];                                                                             \
    __builtin_amdgcn_s_setprio(1);                                                          \
    _Pragma("unroll") for (int nf = 0; nf < 4; ++nf) {                                      \
      f32x4 z = __builtin_amdgcn_mfma_f32_16x16x32_f16(kf[nf][0], qf[0], zacc, 0, 0, 0);    \
      s[nf] = __builtin_amdgcn_mfma_f32_16x16x32_f16(kf[nf][1], qf[1], z, 0, 0, 0);         \
    }                                                                                       \
    __builtin_amdgcn_s_setprio(0);                                                          \
    int wpk[4][2];                                                                          \
    _Pragma("unroll") for (int nf = 0; nf < 4; ++nf) {                                      \
      float p0, p1, p2, p3;                                                                 \
      if (allm) {                                                                           \
        p0 = __builtin_amdgcn_exp2f(s[nf][0]);                                              \
        p1 = __builtin_amdgcn_exp2f(s[nf][1]);                                              \
        p2 = __builtin_amdgcn_exp2f(s[nf][2]);                                              \
        p3 = __builtin_amdgcn_exp2f(s[nf][3]);                                              \
      } else {                                                                              \
        p0 = __builtin_amdgcn_exp2f(MVR[nf].x ? s[nf][0] : MASKVAL);                        \
        p1 = __builtin_amdgcn_exp2f(MVR[nf].y ? s[nf][1] : MASKVAL);                        \
        p2 = __builtin_amdgcn_exp2f(MVR[nf].z ? s[nf][2] : MASKVAL);                        \
        p3 = __builtin_amdgcn_exp2f(MVR[nf].w ? s[nf][3] : MASKVAL);                        \
      }                                                                                     \
      wpk[nf][0] = __builtin_bit_cast(int, __builtin_amdgcn_cvt_pkrtz(p0, p1));             \
      wpk[nf][1] = __builtin_bit_cast(int, __builtin_amdgcn_cvt_pkrtz(p2, p3));             \
    }                                                                                       \
    f16x8 pf[2];                                                                            \
    _Pragma("unroll") for (int k2 = 0; k2 < 2; ++k2) {                                      \
      int A0 = wpk[2 * k2][0], B0 = wpk[2 * k2 + 1][0];                                     \
      int A1 = wpk[2 * k2][1], B1 = wpk[2 * k2 + 1][1];                                     \
      asm("v_permlane32_swap_b32 %0, %1" : "+v"(A0), "+v"(B0));                             \
      asm("v_permlane16_swap_b32 %0, %1" : "+v"(A0), "+v"(B0));                             \
      asm("v_permlane32_swap_b32 %0, %1" : "+v"(A1), "+v"(B1));                             \
      asm("v_permlane16_swap_b32 %0, %1" : "+v"(A1), "+v"(B1));                             \
      i32x4 cc = {A0, A1, B0, B1};                                                          \
      pf[k2] = __builtin_bit_cast(f16x8, cc);                                               \
    }                                                                                       \
    __builtin_amdgcn_s_setprio(1);                                                          \
    _Pragma("unroll") for (int k2 = 0; k2 < 2; ++k2) {                                      \
      _Pragma("unroll") for (int df = 0; df < 4; ++df)                                      \
          oacc[df] = __builtin_amdgcn_mfma_f32_16x16x32_f16(pf[k2], vreg[k2][df], oacc[df], 0, 0, 0); \
      lacc = __builtin_amdgcn_mfma_f32_16x16x32_f16(pf[k2], ones, lacc, 0, 0, 0);           \
    }                                                                                       \
    __builtin_amdgcn_s_setprio(0);                                                          \
  } while (0)

  for (int kt = 0; kt < NT; kt += 2) {
    ATTN_ITER(kt, 0, mvA, mvB);
    ATTN_ITER(kt + 1, 1, mvB, mvA);
  }

  // epilogue: lacc[r] is the row-sum for q = hi*4 + r (all lr identical)
  f32x4 rinv;
#pragma unroll
  for (int r = 0; r < 4; ++r) rinv[r] = 1.0f / lacc[r];
#pragma unroll
  for (int df = 0; df < 4; ++df)
#pragma unroll
    for (int r = 0; r < 4; ++r) {
      const int l = qr0 + hi * 4 + r;
      Oa[(((size_t)b * L + l) * H + h) * HD + df * 16 + lr] = (f16)(oacc[df][r] * rinv[r]);
    }
}

// ---------------------------------------------------------------------------
extern "C" void kernel_launch(void* const* d_in, const int* in_sizes, int n_in,
                              void* d_out, int out_size, void* d_ws, size_t ws_size,
                              hipStream_t stream) {
  const float* x  = (const float*)d_in[0];
  const int* mask = (const int*)d_in[1];
  const float* Wq = (const float*)d_in[2];
  const float* bq = (const float*)d_in[3];
  const float* Wk = (const float*)d_in[4];
  const float* bk = (const float*)d_in[5];
  const float* Wv = (const float*)d_in[6];
  const float* bv = (const float*)d_in[7];
  const float* Wo = (const float*)d_in[8];
  const float* bo = (const float*)d_in[9];
  float* out = (float*)d_out;

  char* ws = (char*)d_ws;
  const size_t MB = 1u << 20;
  f16* xh  = (f16*)(ws);             // 4096x1024  (8 MB)
  f16* wqh = (f16*)(ws + 8 * MB);    // 1024x1024  (2 MB)
  f16* wkh = (f16*)(ws + 10 * MB);
  f16* wvh = (f16*)(ws + 12 * MB);
  f16* woh = (f16*)(ws + 14 * MB);
  f16* qh  = (f16*)(ws + 16 * MB);   // [2][16][2048][64], pre-scaled by ALPHA
  f16* kh  = (f16*)(ws + 24 * MB);   // [2][16][2048][64]
  f16* vfh = (f16*)(ws + 32 * MB);   // [32 heads][32 kvtiles][8 frag][64 lane][8] (8 MB)
  f16* oah = (f16*)(ws + 40 * MB);   // [2][2048][16][64] = [4096][1024]

  conv_all<<<4096, 256, 0, stream>>>(x, Wq, Wk, Wv, Wo, xh, wqh, wkh, wvh, woh);

  gemm_qkv<<<768, 256, 0, stream>>>(xh, wqh, wkh, wvh, bq, bk, bv, qh, kh, vfh);

  attn4w<<<dim3(1024), 256, 0, stream>>>(qh, kh, vfh, mask, oah);

  gemm_o<<<512, 256, 0, stream>>>(oah, woh, bo, out);
}

// Round 14
// 117.074 us; speedup vs baseline: 1.0604x; 1.0604x over previous
//
#include <hip/hip_runtime.h>
#include <hip/hip_bf16.h>

typedef _Float16 f16;
typedef _Float16 f16x8 __attribute__((ext_vector_type(8)));
typedef _Float16 f16x4 __attribute__((ext_vector_type(4)));
typedef float f32x4 __attribute__((ext_vector_type(4)));
typedef int i32x4 __attribute__((ext_vector_type(4)));

#define LDS_LOAD16(gptr, lptr)                                                             \
  __builtin_amdgcn_global_load_lds(                                                        \
      (const __attribute__((address_space(1))) unsigned int*)(gptr),                       \
      (__attribute__((address_space(3))) unsigned int*)(lptr), 16, 0, 0)

// 0.125 (1/sqrt(HD)) * log2(e): folded into Q so QK^T yields log2e-scaled scores
#define ALPHA 0.18033688f
// masked score: reference sets score=1e-9 (log2e domain)
#define MASKVAL 1.44269504e-9f

// ---------------------------------------------------------------------------
// fused fp32 -> fp16 conversion for x + 4 weight matrices
// ---------------------------------------------------------------------------
__global__ __launch_bounds__(256) void conv_all(const float* __restrict__ x,
                                                const float* __restrict__ Wq,
                                                const float* __restrict__ Wk,
                                                const float* __restrict__ Wv,
                                                const float* __restrict__ Wo,
                                                f16* __restrict__ xh, f16* __restrict__ wqh,
                                                f16* __restrict__ wkh, f16* __restrict__ wvh,
                                                f16* __restrict__ woh) {
  int i = blockIdx.x * 256 + threadIdx.x;
  const float* src;
  f16* dst;
  int off;
  if (i < 524288) {
    src = x; dst = xh; off = i;
  } else {
    int j = i - 524288;
    int w = j >> 17;
    off = j & 131071;
    src = (w == 0) ? Wq : (w == 1) ? Wk : (w == 2) ? Wv : Wo;
    dst = (w == 0) ? wqh : (w == 1) ? wkh : (w == 2) ? wvh : woh;
  }
  const float4* s4 = (const float4*)src;
  float4 a = s4[2 * off];
  float4 b = s4[2 * off + 1];
  f16x8 o = {(f16)a.x, (f16)a.y, (f16)a.z, (f16)a.w,
             (f16)b.x, (f16)b.y, (f16)b.z, (f16)b.w};
  *(f16x8*)(dst + (size_t)off * 8) = o;
}

// ---------------------------------------------------------------------------
// Fused QKV projection: z=0 -> Q (scaled by ALPHA), z=1 -> K, z=2 -> V^T.
// 2-phase pipeline, counted vmcnt(4), dbuf LDS, XCD-chunked swizzle.
// ---------------------------------------------------------------------------
__global__ __launch_bounds__(256) void gemm_qkv(const f16* __restrict__ A,
                                                const f16* __restrict__ W0,
                                                const f16* __restrict__ W1,
                                                const f16* __restrict__ W2,
                                                const float* __restrict__ b0,
                                                const float* __restrict__ b1,
                                                const float* __restrict__ b2,
                                                f16* __restrict__ qo, f16* __restrict__ ko,
                                                f16* __restrict__ vo) {
  constexpr int K = 1024, BM = 128, BK = 32, NKT = K / BK;
  __shared__ f16 aT[2][BM * BK];
  __shared__ f16 bT[2][BM * BK];
  const int rid = (blockIdx.x & 7) * 96 + (blockIdx.x >> 3);
  const int z = rid >> 8;
  const f16* Bw = (z == 0) ? W0 : (z == 1) ? W1 : W2;
  const float* bias = (z == 0) ? b0 : (z == 1) ? b1 : b2;
  const int tid = threadIdx.x, wid = tid >> 6, lane = tid & 63;
  const int mb = ((rid >> 3) & 31) * BM, nb = (rid & 7) * BM;
  const int wr = wid >> 1, wc = wid & 1;
  const int lr = lane & 15, hi = lane >> 4;

  f32x4 acc[4][4] = {};

  const int r0 = tid >> 2, s0 = tid & 3;
  const int ci1 = 256 + tid, r1 = ci1 >> 2, s1 = ci1 & 3;

#define STAGE_QKV(bb, kt)                                                                   \
  do {                                                                                      \
    const int kb_ = (kt) * BK;                                                              \
    LDS_LOAD16(A + (size_t)(mb + r0) * K + kb_ + s0 * 8, (char*)aT[bb] + wid * 1024);       \
    LDS_LOAD16(Bw + (size_t)(nb + r0) * K + kb_ + s0 * 8, (char*)bT[bb] + wid * 1024);      \
    LDS_LOAD16(A + (size_t)(mb + r1) * K + kb_ + s1 * 8, (char*)aT[bb] + 4096 + wid * 1024);\
    LDS_LOAD16(Bw + (size_t)(nb + r1) * K + kb_ + s1 * 8, (char*)bT[bb] + 4096 + wid * 1024);\
  } while (0)

  STAGE_QKV(0, 0);
  for (int kt = 0; kt < NKT; ++kt) {
    const int p = kt & 1;
    if (kt + 1 < NKT) {
      STAGE_QKV(p ^ 1, kt + 1);
      asm volatile("s_waitcnt vmcnt(4)" ::: "memory");
    } else {
      asm volatile("s_waitcnt vmcnt(0)" ::: "memory");
    }
    __builtin_amdgcn_s_barrier();

    f16x8 af[4], bf[4];
#pragma unroll
    for (int i = 0; i < 4; ++i) af[i] = *(const f16x8*)&aT[p][(wr * 64 + i * 16 + lr) * BK + hi * 8];
#pragma unroll
    for (int j = 0; j < 4; ++j) bf[j] = *(const f16x8*)&bT[p][(wc * 64 + j * 16 + lr) * BK + hi * 8];
    __builtin_amdgcn_s_setprio(1);
#pragma unroll
    for (int i = 0; i < 4; ++i)
#pragma unroll
      for (int j = 0; j < 4; ++j)
        acc[i][j] = __builtin_amdgcn_mfma_f32_16x16x32_f16(af[i], bf[j], acc[i][j], 0, 0, 0);
    __builtin_amdgcn_s_setprio(0);
    __builtin_amdgcn_s_barrier();
  }

  const float scale = (z == 0) ? ALPHA : 1.0f;
#pragma unroll
  for (int i = 0; i < 4; ++i) {
#pragma unroll
    for (int j = 0; j < 4; ++j) {
      const int row = mb + wr * 64 + i * 16 + hi * 4;
      const int col = nb + wc * 64 + j * 16 + lr;
      const float bv = bias[col];
      const int hh = col >> 6, dd = col & 63;
      if (z == 2) {
        const int bb = row >> 11, l = row & 2047;
        f16x4 v4;
#pragma unroll
        for (int r = 0; r < 4; ++r) v4[r] = (f16)(acc[i][j][r] + bv);
        *(f16x4*)(vo + ((((size_t)bb * 16 + hh) * 64 + dd) * 2048 + l)) = v4;
      } else {
        f16* o = z ? ko : qo;
#pragma unroll
        for (int r = 0; r < 4; ++r) {
          const int m2 = row + r;
          const int bb = m2 >> 11, l = m2 & 2047;
          o[((((size_t)bb * 16 + hh) * 2048 + l) * 64) + dd] = (f16)((acc[i][j][r] + bv) * scale);
        }
      }
    }
  }
}

// ---------------------------------------------------------------------------
// Output projection: 64(M)x128(N) tile, 2-phase pipeline, XCD-chunked swizzle.
// ---------------------------------------------------------------------------
__global__ __launch_bounds__(256) void gemm_o(const f16* __restrict__ A,
                                              const f16* __restrict__ W,
                                              const float* __restrict__ bias,
                                              float* __restrict__ out) {
  constexpr int K = 1024, N = 1024, BK = 32, NKT = K / BK;
  __shared__ f16 aT[2][64 * BK];
  __shared__ f16 bT[2][128 * BK];
  const int rid = (blockIdx.x & 7) * 64 + (blockIdx.x >> 3);
  const int tid = threadIdx.x, wid = tid >> 6, lane = tid & 63;
  const int lr = lane & 15, hi = lane >> 4;
  const int mb = (rid >> 3) * 64, nb = (rid & 7) * 128;
  const int wr = wid >> 1, wc = wid & 1;
  f32x4 acc[2][4] = {};
  const int ra = tid >> 2, sa = tid & 3;
  const int rb1 = (256 + tid) >> 2, sb1 = (256 + tid) & 3;

#define STAGE_O(bb, kt)                                                                     \
  do {                                                                                      \
    const int kb_ = (kt) * BK;                                                              \
    LDS_LOAD16(A + (size_t)(mb + ra) * K + kb_ + sa * 8, (char*)aT[bb] + wid * 1024);       \
    LDS_LOAD16(W + (size_t)(nb + ra) * K + kb_ + sa * 8, (char*)bT[bb] + wid * 1024);       \
    LDS_LOAD16(W + (size_t)(nb + rb1) * K + kb_ + sb1 * 8, (char*)bT[bb] + 4096 + wid * 1024);\
  } while (0)

  STAGE_O(0, 0);
  for (int kt = 0; kt < NKT; ++kt) {
    const int p = kt & 1;
    if (kt + 1 < NKT) {
      STAGE_O(p ^ 1, kt + 1);
      asm volatile("s_waitcnt vmcnt(3)" ::: "memory");
    } else {
      asm volatile("s_waitcnt vmcnt(0)" ::: "memory");
    }
    __builtin_amdgcn_s_barrier();
    f16x8 af[2], bf[4];
#pragma unroll
    for (int i = 0; i < 2; ++i) af[i] = *(const f16x8*)&aT[p][(wr * 32 + i * 16 + lr) * BK + hi * 8];
#pragma unroll
    for (int j = 0; j < 4; ++j) bf[j] = *(const f16x8*)&bT[p][(wc * 64 + j * 16 + lr) * BK + hi * 8];
    __builtin_amdgcn_s_setprio(1);
#pragma unroll
    for (int i = 0; i < 2; ++i)
#pragma unroll
      for (int j = 0; j < 4; ++j)
        acc[i][j] = __builtin_amdgcn_mfma_f32_16x16x32_f16(af[i], bf[j], acc[i][j], 0, 0, 0);
    __builtin_amdgcn_s_setprio(0);
    __builtin_amdgcn_s_barrier();
  }
#pragma unroll
  for (int i = 0; i < 2; ++i)
#pragma unroll
    for (int j = 0; j < 4; ++j) {
      const int col = nb + wc * 64 + j * 16 + lr;
      const float bv = bias[col];
#pragma unroll
      for (int r = 0; r < 4; ++r)
        out[(size_t)(mb + wr * 32 + i * 16 + hi * 4 + r) * N + col] = acc[i][j][r] + bv;
    }
}

// ---------------------------------------------------------------------------
// Flash attention v8 (kv-split hybrid): 4 waves = 2(kv-half) x 2(q-half).
// Wave (wk,wq) computes PARTIAL O for q rows [wq*32,wq*32+32) over kv slice
// [wk*32,wk*32+32) of each 64-KV tile -> each wave reads only 8 KB/tile
// (K slice 4 b128 + V^T slice 4 b128): block DS reads halve vs v5.
// Partial O/lsum pairs (wk=0 <- wk=1) reduced ONCE at kernel end through the
// dead staging LDS.  All fragment layouts + permlane32/16 P-transpose reused
// verbatim from r11 (session-verified).  dbuf staging, 1 barrier/tile,
// p = exp2(score*log2e) (Q pre-scaled by ALPHA), mask all-ones fast path.
// ---------------------------------------------------------------------------
__global__ __launch_bounds__(256, 4) void attn4w(const f16* __restrict__ Qh,
                                                 const f16* __restrict__ Kh,
                                                 const f16* __restrict__ Vt,
                                                 const int* __restrict__ mask,
                                                 f16* __restrict__ Oa) {
  constexpr int L = 2048, HD = 64, H = 16, NT = L / 64;
  // [parity][ K 8KB | V^T 8KB ] = 32 KB; reused as reduction scratch at end
  __shared__ __align__(16) char ldsb[32768];

  const int tid = threadIdx.x, wid = tid >> 6, lane = tid & 63;
  const int wk = wid >> 1, wq = wid & 1;
  const int lr = lane & 15, hi = lane >> 4;
  const int sw = lr & 7;

  // XCD-bijective remap: bid bits [2:0]=xcd, [7:3]=qb, [9:8]=head-in-xcd
  const int bid = blockIdx.x;  // 1024 blocks
  const int head = (bid & 7) * 4 + (bid >> 8);
  const int qb = (bid >> 3) & 31;
  const int b = head >> 4, h = head & 15;
  const int qr0 = qb * 64 + wq * 32;

  const f16* Qb = Qh + (size_t)head * L * HD;
  const f16* Kb = Kh + (size_t)head * L * HD;
  const f16* Vb = Vt + (size_t)head * HD * L;
  const int* mrow = mask + b * L;

  // whole-row mask scan (wave-uniform fast path; mask is 0/1 ints)
  int mred = 1;
  {
    const int4* m4 = (const int4*)mrow;
#pragma unroll
    for (int j = 0; j < 8; ++j) {
      int4 v = m4[lane + j * 64];
      mred &= v.x & v.y & v.z & v.w;
    }
  }
  const bool allm = __all(mred == 1);

  // staging: wave wid stages K rows [wid*16, wid*16+16) and V^T rows likewise
  const int srow = lane >> 3;
  const int schk = (lane & 7) ^ srow;

#define STAGE_KV(bb, kt)                                                                    \
  _Pragma("unroll") for (int c = 0; c < 2; ++c) {                                           \
    LDS_LOAD16(Kb + (size_t)((kt) * 64 + wid * 16 + c * 8 + srow) * HD + schk * 8,          \
               ldsb + (bb) * 16384 + wid * 2048 + c * 1024);                                \
    LDS_LOAD16(Vb + (size_t)(wid * 16 + c * 8 + srow) * L + (kt) * 64 + schk * 8,           \
               ldsb + (bb) * 16384 + 8192 + wid * 2048 + c * 1024);                         \
  }

  // K read bases: row = wk*32 + kvg*16 + lr (kvg via +2048), chunk (k2*4+hi)^sw
  const char* kbase0 = ldsb + (wk * 32 + lr) * 128 + ((hi ^ sw) * 16);
  const char* kbase1 = ldsb + (wk * 32 + lr) * 128 + (((4 + hi) ^ sw) * 16);
  // V^T read base: row d = df*16 + lr (df via +2048), chunk ((wk*4+hi)^sw)
  const char* vbase = ldsb + 8192 + lr * 128 + (((wk * 4 + hi) ^ sw) * 16);

  // Q fragments (B-operand): q = qr0 + qg*16 + lr, k = k2*32 + hi*8..
  f16x8 qf[2][2];
#pragma unroll
  for (int qg = 0; qg < 2; ++qg)
#pragma unroll
    for (int k2 = 0; k2 < 2; ++k2)
      qf[qg][k2] = *(const f16x8*)&Qb[(size_t)(qr0 + qg * 16 + lr) * HD + k2 * 32 + hi * 8];

  f32x4 oacc[2][4] = {};
  f32x4 lacc[2] = {};
  const f32x4 zacc = {0.f, 0.f, 0.f, 0.f};
  const f16x8 ones = {1, 1, 1, 1, 1, 1, 1, 1};

  int4 mvA[2], mvB[2];
  if (!allm) {
#pragma unroll
    for (int kvg = 0; kvg < 2; ++kvg)
      mvA[kvg] = *(const int4*)&mrow[wk * 32 + kvg * 16 + hi * 4];
  }
  STAGE_KV(0, 0);

#define ATTN_ITER(kt, P, MVR, MVL)                                                          \
  do {                                                                                      \
    asm volatile("s_waitcnt vmcnt(0)" ::: "memory");                                        \
    __builtin_amdgcn_s_barrier();                                                           \
    if ((kt) + 1 < NT) {                                                                    \
      if (!allm) {                                                                          \
        _Pragma("unroll") for (int kvg = 0; kvg < 2; ++kvg)                                 \
            MVL[kvg] = *(const int4*)&mrow[((kt) + 1) * 64 + wk * 32 + kvg * 16 + hi * 4];  \
      }                                                                                     \
      STAGE_KV((P) ^ 1, (kt) + 1);                                                          \
    }                                                                                       \
    f16x8 kf[2][2];                                                                         \
    _Pragma("unroll") for (int kvg = 0; kvg < 2; ++kvg) {                                   \
      kf[kvg][0] = *(const f16x8*)(kbase0 + (P) * 16384 + kvg * 2048);                      \
      kf[kvg][1] = *(const f16x8*)(kbase1 + (P) * 16384 + kvg * 2048);                      \
    }                                                                                       \
    f32x4 s[2][2];                                                                          \
    __builtin_amdgcn_s_setprio(1);                                                          \
    _Pragma("unroll") for (int qg = 0; qg < 2; ++qg)                                        \
        _Pragma("unroll") for (int kvg = 0; kvg < 2; ++kvg) {                               \
      f32x4 z = __builtin_amdgcn_mfma_f32_16x16x32_f16(kf[kvg][0], qf[qg][0], zacc, 0, 0, 0);\
      s[qg][kvg] = __builtin_amdgcn_mfma_f32_16x16x32_f16(kf[kvg][1], qf[qg][1], z, 0, 0, 0);\
    }                                                                                       \
    __builtin_amdgcn_s_setprio(0);                                                          \
    f16x8 pf[2];                                                                            \
    _Pragma("unroll") for (int qg = 0; qg < 2; ++qg) {                                      \
      int wpk[2][2];                                                                        \
      _Pragma("unroll") for (int kvg = 0; kvg < 2; ++kvg) {                                 \
        float p0, p1, p2, p3;                                                               \
        if (allm) {                                                                         \
          p0 = __builtin_amdgcn_exp2f(s[qg][kvg][0]);                                       \
          p1 = __builtin_amdgcn_exp2f(s[qg][kvg][1]);                                       \
          p2 = __builtin_amdgcn_exp2f(s[qg][kvg][2]);                                       \
          p3 = __builtin_amdgcn_exp2f(s[qg][kvg][3]);                                       \
        } else {                                                                            \
          p0 = __builtin_amdgcn_exp2f(MVR[kvg].x ? s[qg][kvg][0] : MASKVAL);                \
          p1 = __builtin_amdgcn_exp2f(MVR[kvg].y ? s[qg][kvg][1] : MASKVAL);                \
          p2 = __builtin_amdgcn_exp2f(MVR[kvg].z ? s[qg][kvg][2] : MASKVAL);                \
          p3 = __builtin_amdgcn_exp2f(MVR[kvg].w ? s[qg][kvg][3] : MASKVAL);                \
        }                                                                                   \
        wpk[kvg][0] = __builtin_bit_cast(int, __builtin_amdgcn_cvt_pkrtz(p0, p1));          \
        wpk[kvg][1] = __builtin_bit_cast(int, __builtin_amdgcn_cvt_pkrtz(p2, p3));          \
      }                                                                                     \
      int A0 = wpk[0][0], B0 = wpk[1][0];                                                   \
      int A1 = wpk[0][1], B1 = wpk[1][1];                                                   \
      asm("v_permlane32_swap_b32 %0, %1" : "+v"(A0), "+v"(B0));                             \
      asm("v_permlane16_swap_b32 %0, %1" : "+v"(A0), "+v"(B0));                             \
      asm("v_permlane32_swap_b32 %0, %1" : "+v"(A1), "+v"(B1));                             \
      asm("v_permlane16_swap_b32 %0, %1" : "+v"(A1), "+v"(B1));                             \
      i32x4 cc = {A0, A1, B0, B1};                                                          \
      pf[qg] = __builtin_bit_cast(f16x8, cc);                                               \
    }                                                                                       \
    f16x8 vf[4];                                                                            \
    _Pragma("unroll") for (int df = 0; df < 4; ++df)                                        \
        vf[df] = *(const f16x8*)(vbase + (P) * 16384 + df * 2048);                          \
    __builtin_amdgcn_s_setprio(1);                                                          \
    _Pragma("unroll") for (int qg = 0; qg < 2; ++qg) {                                      \
      _Pragma("unroll") for (int df = 0; df < 4; ++df)                                      \
          oacc[qg][df] = __builtin_amdgcn_mfma_f32_16x16x32_f16(pf[qg], vf[df], oacc[qg][df], 0, 0, 0); \
      lacc[qg] = __builtin_amdgcn_mfma_f32_16x16x32_f16(pf[qg], ones, lacc[qg], 0, 0, 0);   \
    }                                                                                       \
    __builtin_amdgcn_s_setprio(0);                                                          \
  } while (0)

  for (int kt = 0; kt < NT; kt += 2) {
    ATTN_ITER(kt, 0, mvA, mvB);
    ATTN_ITER(kt + 1, 1, mvB, mvA);
  }

  // ---- cross-wave (wk) reduction through the dead staging LDS ----
  __syncthreads();
  if (wk == 1) {
#pragma unroll
    for (int qg = 0; qg < 2; ++qg) {
#pragma unroll
      for (int df = 0; df < 4; ++df)
        *(f32x4*)(ldsb + wq * 8192 + (qg * 4 + df) * 1024 + lane * 16) = oacc[qg][df];
      *(f32x4*)(ldsb + 16384 + (wq * 2 + qg) * 1024 + lane * 16) = lacc[qg];
    }
  }
  __syncthreads();
  if (wk == 0) {
#pragma unroll
    for (int qg = 0; qg < 2; ++qg) {
#pragma unroll
      for (int df = 0; df < 4; ++df)
        oacc[qg][df] += *(const f32x4*)(ldsb + wq * 8192 + (qg * 4 + df) * 1024 + lane * 16);
      lacc[qg] += *(const f32x4*)(ldsb + 16384 + (wq * 2 + qg) * 1024 + lane * 16);
    }
    // epilogue: lacc[qg][r] is the row-sum for q = qg*16 + hi*4 + r
#pragma unroll
    for (int qg = 0; qg < 2; ++qg) {
      f32x4 rinv;
#pragma unroll
      for (int r = 0; r < 4; ++r) rinv[r] = 1.0f / lacc[qg][r];
#pragma unroll
      for (int df = 0; df < 4; ++df)
#pragma unroll
        for (int r = 0; r < 4; ++r) {
          const int l = qr0 + qg * 16 + hi * 4 + r;
          Oa[(((size_t)b * L + l) * H + h) * HD + df * 16 + lr] =
              (f16)(oacc[qg][df][r] * rinv[r]);
        }
    }
  }
}

// ---------------------------------------------------------------------------
extern "C" void kernel_launch(void* const* d_in, const int* in_sizes, int n_in,
                              void* d_out, int out_size, void* d_ws, size_t ws_size,
                              hipStream_t stream) {
  const float* x  = (const float*)d_in[0];
  const int* mask = (const int*)d_in[1];
  const float* Wq = (const float*)d_in[2];
  const float* bq = (const float*)d_in[3];
  const float* Wk = (const float*)d_in[4];
  const float* bk = (const float*)d_in[5];
  const float* Wv = (const float*)d_in[6];
  const float* bv = (const float*)d_in[7];
  const float* Wo = (const float*)d_in[8];
  const float* bo = (const float*)d_in[9];
  float* out = (float*)d_out;

  char* ws = (char*)d_ws;
  const size_t MB = 1u << 20;
  f16* xh  = (f16*)(ws);             // 4096x1024  (8 MB)
  f16* wqh = (f16*)(ws + 8 * MB);    // 1024x1024  (2 MB)
  f16* wkh = (f16*)(ws + 10 * MB);
  f16* wvh = (f16*)(ws + 12 * MB);
  f16* woh = (f16*)(ws + 14 * MB);
  f16* qh  = (f16*)(ws + 16 * MB);   // [2][16][2048][64], pre-scaled by ALPHA
  f16* kh  = (f16*)(ws + 24 * MB);   // [2][16][2048][64]
  f16* vth = (f16*)(ws + 32 * MB);   // [2][16][64][2048]
  f16* oah = (f16*)(ws + 40 * MB);   // [2][2048][16][64] = [4096][1024]

  conv_all<<<4096, 256, 0, stream>>>(x, Wq, Wk, Wv, Wo, xh, wqh, wkh, wvh, woh);

  gemm_qkv<<<768, 256, 0, stream>>>(xh, wqh, wkh, wvh, bq, bk, bv, qh, kh, vth);

  attn4w<<<dim3(1024), 256, 0, stream>>>(qh, kh, vth, mask, oah);

  gemm_o<<<512, 256, 0, stream>>>(oah, woh, bo, out);
}